// Round 1
// baseline (1320.747 us; speedup 1.0000x reference)
//
#include <hip/hip_runtime.h>
#include <stdint.h>

constexpr int B_ = 64, N_ = 2048, D_ = 256, H_ = 64;
constexpr int M_ = B_ * N_;           // 131072 rows
constexpr int TOPK_ = 204, TOP5_ = 102;
constexpr float NEGINF_ = -1e30f;

// out layout (floats)
constexpr int OUT_BAG  = 0;                      // 64*512
constexpr int OUT_ATTN = 32768;                  // 64*3*2048
constexpr int OUT_AVG  = OUT_ATTN + 393216;      // 425984
constexpr int OUT_TOPK = OUT_AVG + 131072;       // 557056
constexpr int OUT_ENT  = OUT_TOPK + 131072;      // 688128
constexpr int OUT_EFF  = OUT_ENT + 64;           // 688192
constexpr int OUT_T5   = OUT_EFF + 64;           // 688256

// ws layout (floats)
constexpr int WS_TK    = 0;                      // 131072
constexpr int WS_SC    = 131072;                 // [s*64+b][n] : 393216
constexpr int WS_STATS = WS_SC + 393216;         // 524288 : [b]=valid_sum, [64+b]=topk_sum
constexpr int WS_PART  = WS_STATS + 128;         // 524416 : [b*8+ch][5][256] = 655360
constexpr int WS_CAT   = WS_PART + 655360;       // 1179776 : [b][1280]

__device__ __forceinline__ float block_sum256(float v, volatile float* red, int t) {
    #pragma unroll
    for (int off = 32; off; off >>= 1) v += __shfl_xor(v, off, 64);
    __syncthreads();
    if ((t & 63) == 0) red[t >> 6] = v;
    __syncthreads();
    return red[0] + red[1] + red[2] + red[3];
}
__device__ __forceinline__ float block_max256(float v, volatile float* red, int t) {
    #pragma unroll
    for (int off = 32; off; off >>= 1) v = fmaxf(v, __shfl_xor(v, off, 64));
    __syncthreads();
    if ((t & 63) == 0) red[t >> 6] = v;
    __syncthreads();
    return fmaxf(fmaxf(red[0], red[1]), fmaxf(red[2], red[3]));
}

// ---------------- K1: fused scorer + 3 attention-branch hidden GEMM ----------------
// C = X[131072x256] @ W[256x256], W = [Ws1 | Wa1_0 | Wa1_1 | Wa1_2]; then
// per-row: relu/tanh + second-layer dot (wave reduce over 64 hidden units/lane).
__global__ __launch_bounds__(256, 3)
void k_scores(const float* __restrict__ inst, const float* __restrict__ mask,
              const float* __restrict__ Ws1, const float* __restrict__ bs1,
              const float* __restrict__ Ws2, const float* __restrict__ bs2,
              const float* __restrict__ Wa1, const float* __restrict__ ba1,
              const float* __restrict__ Wa2, const float* __restrict__ ba2,
              float* __restrict__ ws)
{
    constexpr int KC = 32;
    __shared__ float Wl[KC][256];               // 32 KB
    const int t = threadIdx.x;
    const int wv = t >> 6, l = t & 63;
    const int row0 = blockIdx.x * 64;

    float acc[16][4];
    #pragma unroll
    for (int r = 0; r < 16; ++r) {
        #pragma unroll
        for (int s = 0; s < 4; ++s) acc[r][s] = 0.0f;
    }

    const float* xbase = inst + (size_t)(row0 + wv * 16) * D_;

    for (int k0 = 0; k0 < D_; k0 += KC) {
        // stage W chunk: Wl[k][c], c = set*64 + h  (coalesced float4 global reads)
        #pragma unroll
        for (int i = 0; i < 8; ++i) {
            int fi = i * 256 + t;               // 0..2047
            int k = fi >> 6;                    // 0..31
            int c4 = (fi & 63) * 4;             // 0..252
            int s = c4 >> 6, h = c4 & 63;
            const float* src = (s == 0)
                ? (Ws1 + (size_t)(k0 + k) * H_ + h)
                : (Wa1 + ((size_t)(s - 1) * D_ + (k0 + k)) * H_ + h);
            *(float4*)&Wl[k][c4] = *(const float4*)src;
        }
        __syncthreads();
        #pragma unroll 2
        for (int u = 0; u < KC / 4; ++u) {
            float w[4][4];
            #pragma unroll
            for (int j = 0; j < 4; ++j) {
                w[0][j] = Wl[u * 4 + j][l];
                w[1][j] = Wl[u * 4 + j][64 + l];
                w[2][j] = Wl[u * 4 + j][128 + l];
                w[3][j] = Wl[u * 4 + j][192 + l];
            }
            #pragma unroll
            for (int r = 0; r < 16; ++r) {
                float4 x = *(const float4*)(xbase + (size_t)r * D_ + k0 + u * 4);
                #pragma unroll
                for (int s = 0; s < 4; ++s) {
                    acc[r][s] = fmaf(x.x, w[s][0], acc[r][s]);
                    acc[r][s] = fmaf(x.y, w[s][1], acc[r][s]);
                    acc[r][s] = fmaf(x.z, w[s][2], acc[r][s]);
                    acc[r][s] = fmaf(x.w, w[s][3], acc[r][s]);
                }
            }
        }
        __syncthreads();
    }

    const float bs1_l = bs1[l], ws2_l = Ws2[l], bs2_v = bs2[0];
    float ba1_l[3], wa2_l[3], ba2_v[3];
    #pragma unroll
    for (int s = 0; s < 3; ++s) {
        ba1_l[s] = ba1[s * H_ + l];
        wa2_l[s] = Wa2[s * H_ + l];
        ba2_v[s] = ba2[s];
    }
    #pragma unroll
    for (int r = 0; r < 16; ++r) {
        const int gr = row0 + wv * 16 + r;
        float h0 = acc[r][0] + bs1_l;
        h0 = h0 > 0.0f ? h0 : 0.0f;
        float red0 = h0 * ws2_l;
        float red1 = tanhf(acc[r][1] + ba1_l[0]) * wa2_l[0];
        float red2 = tanhf(acc[r][2] + ba1_l[1]) * wa2_l[1];
        float red3 = tanhf(acc[r][3] + ba1_l[2]) * wa2_l[2];
        #pragma unroll
        for (int off = 32; off; off >>= 1) {
            red0 += __shfl_xor(red0, off, 64);
            red1 += __shfl_xor(red1, off, 64);
            red2 += __shfl_xor(red2, off, 64);
            red3 += __shfl_xor(red3, off, 64);
        }
        if (l == 0) {
            const bool inv = (mask[gr] == 0.0f);
            ws[WS_TK + gr]          = inv ? NEGINF_ : (red0 + bs2_v);
            ws[WS_SC + 0 * M_ + gr] = inv ? NEGINF_ : (red1 + ba2_v[0]);
            ws[WS_SC + 1 * M_ + gr] = inv ? NEGINF_ : (red2 + ba2_v[1]);
            ws[WS_SC + 2 * M_ + gr] = inv ? NEGINF_ : (red3 + ba2_v[2]);
        }
    }
}

// ---------------- K2: per-batch top-204 via bitonic sort ----------------
__global__ __launch_bounds__(256)
void k_topk(const float* __restrict__ ws_tk, const float* __restrict__ mask,
            float* __restrict__ out_topk, float* __restrict__ ws_stats)
{
    __shared__ unsigned long long key[N_];      // 16 KB
    __shared__ float red[4];
    const int b = blockIdx.x, t = threadIdx.x;
    float vsum = 0.0f;
    for (int i = t; i < N_; i += 256) {
        float f = ws_tk[b * N_ + i];
        unsigned u = __float_as_uint(f);
        u = (u & 0x80000000u) ? ~u : (u | 0x80000000u);
        // ascending sort; ties: value asc, and for equal value larger (N-1-i) = smaller i ranks higher
        key[i] = ((unsigned long long)u << 32) | (unsigned)(N_ - 1 - i);
        vsum += mask[b * N_ + i];
        out_topk[b * N_ + i] = 0.0f;
    }
    float vs = block_sum256(vsum, red, t);
    if (t == 0) ws_stats[b] = vs;
    __syncthreads();
    for (int k = 2; k <= N_; k <<= 1) {
        for (int j = k >> 1; j > 0; j >>= 1) {
            for (int i = t; i < N_; i += 256) {
                int ij = i ^ j;
                if (ij > i) {
                    unsigned long long a = key[i], c = key[ij];
                    if ((a > c) == ((i & k) == 0)) { key[i] = c; key[ij] = a; }
                }
            }
            __syncthreads();
        }
    }
    float csum = 0.0f;
    for (int i = t; i < TOPK_; i += 256) {
        unsigned long long kk = key[N_ - 1 - i];
        int n = N_ - 1 - (int)(unsigned)(kk & 0xffffffffu);
        out_topk[b * N_ + n] = 1.0f;
        csum += mask[b * N_ + n];
    }
    float cs = block_sum256(csum, red, t);
    if (t == 0) ws_stats[64 + b] = cs;
}

// ---------------- K3: softmax per (branch, batch) ----------------
__global__ __launch_bounds__(256)
void k_softmax(const float* __restrict__ ws_sc, float* __restrict__ out_attn)
{
    __shared__ float red[4];
    const int sb = blockIdx.x;                  // s*64 + b
    const int s = sb >> 6, b = sb & 63;
    const int t = threadIdx.x;
    const float* src = ws_sc + (size_t)sb * N_;
    float fv[8];
    float mx = -3.4e38f;
    #pragma unroll
    for (int m = 0; m < 8; ++m) { fv[m] = src[t + 256 * m]; mx = fmaxf(mx, fv[m]); }
    float bm = block_max256(mx, red, t);
    float sm = 0.0f;
    #pragma unroll
    for (int m = 0; m < 8; ++m) { fv[m] = expf(fv[m] - bm); sm += fv[m]; }
    float tot = block_sum256(sm, red, t);
    float inv = 1.0f / tot;
    float* dst = out_attn + ((size_t)b * 3 + s) * N_;
    #pragma unroll
    for (int m = 0; m < 8; ++m) dst[t + 256 * m] = fv[m] * inv;
}

// ---------------- K4: pooling partials (mean, topk, 3 branches) ----------------
__global__ __launch_bounds__(256)
void k_pool(const float* __restrict__ inst, const float* __restrict__ mask,
            const float* __restrict__ out_topk, const float* __restrict__ out_attn,
            float* __restrict__ ws_part)
{
    __shared__ float wgt[5][256];
    const int blk = blockIdx.x;                 // b*8 + ch
    const int b = blk >> 3, ch = blk & 7;
    const int n0 = ch * 256;
    const int t = threadIdx.x;                  // = d
    {
        float mv = mask[b * N_ + n0 + t];
        wgt[0][t] = mv;
        wgt[1][t] = out_topk[b * N_ + n0 + t] * mv;
        const float* ab = out_attn + (size_t)b * 3 * N_ + n0 + t;
        wgt[2][t] = ab[0];
        wgt[3][t] = ab[N_];
        wgt[4][t] = ab[2 * N_];
    }
    __syncthreads();
    float a0 = 0, a1 = 0, a2 = 0, a3 = 0, a4 = 0;
    const float* xp = inst + ((size_t)b * N_ + n0) * D_ + t;
    #pragma unroll 4
    for (int nn = 0; nn < 256; ++nn) {
        float x = xp[(size_t)nn * D_];
        a0 = fmaf(x, wgt[0][nn], a0);
        a1 = fmaf(x, wgt[1][nn], a1);
        a2 = fmaf(x, wgt[2][nn], a2);
        a3 = fmaf(x, wgt[3][nn], a3);
        a4 = fmaf(x, wgt[4][nn], a4);
    }
    float* pp = ws_part + (size_t)blk * 1280 + t;
    pp[0] = a0; pp[256] = a1; pp[512] = a2; pp[768] = a3; pp[1024] = a4;
}

// ---------------- K5: reduce partials -> cat[b][1280] with scaling ----------------
__global__ __launch_bounds__(256)
void k_cat(const float* __restrict__ ws_part, const float* __restrict__ ws_stats,
           float* __restrict__ ws_cat)
{
    const int idx = blockIdx.x * 256 + threadIdx.x;
    if (idx >= B_ * 1280) return;
    const int b = idx / 1280, rem = idx % 1280;
    const int j = rem >> 8, d = rem & 255;
    float s = 0.0f;
    #pragma unroll
    for (int c = 0; c < 8; ++c)
        s += ws_part[((size_t)(b * 8 + c) * 5 + j) * 256 + d];
    if (j == 0)      s /= fmaxf(ws_stats[b], 1.0f);
    else if (j == 1) s /= fmaxf(ws_stats[64 + b], 1.0f);
    ws_cat[idx] = s;
}

// ---------------- K6: diagnostics (avg_attn, entropy, effective_n, top5) ----------------
__global__ __launch_bounds__(256)
void k_diag(const float* __restrict__ out_attn, float* __restrict__ out_avg,
            float* __restrict__ out_ent, float* __restrict__ out_eff,
            float* __restrict__ out_t5)
{
    __shared__ unsigned long long key[N_];
    __shared__ float red[4];
    const int b = blockIdx.x, t = threadIdx.x;
    const float* a0 = out_attn + (size_t)b * 3 * N_;
    float esum = 0.0f, qsum = 0.0f;
    for (int i = t; i < N_; i += 256) {
        float a = (a0[i] + a0[N_ + i] + a0[2 * N_ + i]) * (1.0f / 3.0f);
        out_avg[b * N_ + i] = a;
        esum -= a * logf(a + 1e-8f);
        qsum += a * a;
        unsigned u = __float_as_uint(a);
        u = (u & 0x80000000u) ? ~u : (u | 0x80000000u);
        key[i] = ((unsigned long long)u << 32) | (unsigned)i;
    }
    float es = block_sum256(esum, red, t);
    float qs = block_sum256(qsum, red, t);
    if (t == 0) { out_ent[b] = es; out_eff[b] = 1.0f / qs; }
    __syncthreads();
    for (int k = 2; k <= N_; k <<= 1) {
        for (int j = k >> 1; j > 0; j >>= 1) {
            for (int i = t; i < N_; i += 256) {
                int ij = i ^ j;
                if (ij > i) {
                    unsigned long long x = key[i], y = key[ij];
                    if ((x > y) == ((i & k) == 0)) { key[i] = y; key[ij] = x; }
                }
            }
            __syncthreads();
        }
    }
    if (t == 0) {
        float s5 = 0.0f;
        for (int i = 0; i < TOP5_; ++i) {
            unsigned ou = (unsigned)(key[N_ - 1 - i] >> 32);
            unsigned bits = (ou & 0x80000000u) ? (ou & 0x7fffffffu) : ~ou;
            s5 += __uint_as_float(bits);
        }
        out_t5[b] = s5;
    }
}

// ---------------- K7: fusion MLP (Linear -> LN -> GELU(erf) -> Linear) ----------------
__global__ __launch_bounds__(256)
void k_fusion(const float* __restrict__ ws_cat, const float* __restrict__ Wf1,
              const float* __restrict__ bf1, const float* __restrict__ ln_g,
              const float* __restrict__ ln_b, const float* __restrict__ Wf2,
              const float* __restrict__ bf2, float* __restrict__ out_bag)
{
    __shared__ float cl[1280];
    __shared__ float gl[512];
    __shared__ float red[4];
    const int b = blockIdx.x, t = threadIdx.x;
    for (int i = t; i < 1280; i += 256) cl[i] = ws_cat[b * 1280 + i];
    __syncthreads();
    float x0 = bf1[t], x1 = bf1[t + 256];
    #pragma unroll 4
    for (int k = 0; k < 1280; ++k) {
        float cv = cl[k];
        x0 = fmaf(cv, Wf1[(size_t)k * 512 + t], x0);
        x1 = fmaf(cv, Wf1[(size_t)k * 512 + t + 256], x1);
    }
    float mu = block_sum256(x0 + x1, red, t) * (1.0f / 512.0f);
    float v0 = x0 - mu, v1 = x1 - mu;
    float var = block_sum256(v0 * v0 + v1 * v1, red, t) * (1.0f / 512.0f);
    float is = 1.0f / sqrtf(var + 1e-5f);
    float y0 = v0 * is * ln_g[t] + ln_b[t];
    float y1 = v1 * is * ln_g[t + 256] + ln_b[t + 256];
    float g0 = 0.5f * y0 * (1.0f + erff(y0 * 0.70710678118654752440f));
    float g1 = 0.5f * y1 * (1.0f + erff(y1 * 0.70710678118654752440f));
    gl[t] = g0; gl[t + 256] = g1;
    __syncthreads();
    float o0 = bf2[t], o1 = bf2[t + 256];
    #pragma unroll 4
    for (int k = 0; k < 512; ++k) {
        float gv = gl[k];
        o0 = fmaf(gv, Wf2[(size_t)k * 512 + t], o0);
        o1 = fmaf(gv, Wf2[(size_t)k * 512 + t + 256], o1);
    }
    out_bag[b * 512 + t] = o0;
    out_bag[b * 512 + t + 256] = o1;
}

extern "C" void kernel_launch(void* const* d_in, const int* in_sizes, int n_in,
                              void* d_out, int out_size, void* d_ws, size_t ws_size,
                              hipStream_t stream)
{
    (void)in_sizes; (void)n_in; (void)out_size; (void)ws_size;
    const float* inst = (const float*)d_in[0];
    const float* mask = (const float*)d_in[1];
    const float* Ws1  = (const float*)d_in[2];
    const float* bs1  = (const float*)d_in[3];
    const float* Ws2  = (const float*)d_in[4];
    const float* bs2  = (const float*)d_in[5];
    const float* Wa1  = (const float*)d_in[6];
    const float* ba1  = (const float*)d_in[7];
    const float* Wa2  = (const float*)d_in[8];
    const float* ba2  = (const float*)d_in[9];
    const float* Wf1  = (const float*)d_in[10];
    const float* bf1  = (const float*)d_in[11];
    const float* lng  = (const float*)d_in[12];
    const float* lnb  = (const float*)d_in[13];
    const float* Wf2  = (const float*)d_in[14];
    const float* bf2  = (const float*)d_in[15];

    float* out = (float*)d_out;
    float* ws  = (float*)d_ws;

    k_scores<<<M_ / 64, 256, 0, stream>>>(inst, mask, Ws1, bs1, Ws2, bs2,
                                          Wa1, ba1, Wa2, ba2, ws);
    k_topk<<<B_, 256, 0, stream>>>(ws + WS_TK, mask, out + OUT_TOPK, ws + WS_STATS);
    k_softmax<<<3 * B_, 256, 0, stream>>>(ws + WS_SC, out + OUT_ATTN);
    k_pool<<<B_ * 8, 256, 0, stream>>>(inst, mask, out + OUT_TOPK, out + OUT_ATTN,
                                       ws + WS_PART);
    k_diag<<<B_, 256, 0, stream>>>(out + OUT_ATTN, out + OUT_AVG, out + OUT_ENT,
                                   out + OUT_EFF, out + OUT_T5);
    k_cat<<<(B_ * 1280 + 255) / 256, 256, 0, stream>>>(ws + WS_PART, ws + WS_STATS,
                                                       ws + WS_CAT);
    k_fusion<<<B_, 256, 0, stream>>>(ws + WS_CAT, Wf1, bf1, lng, lnb, Wf2, bf2,
                                     out + OUT_BAG);
}

// Round 3
// 598.619 us; speedup vs baseline: 2.2063x; 2.2063x over previous
//
#include <hip/hip_runtime.h>
#include <stdint.h>

constexpr int B_ = 64, N_ = 2048, D_ = 256, H_ = 64;
constexpr int M_ = B_ * N_;           // 131072 rows
constexpr int TOPK_ = 204, TOP5_ = 102;
constexpr float NEGINF_ = -1e30f;

// out layout (floats)
constexpr int OUT_BAG  = 0;                      // 64*512
constexpr int OUT_ATTN = 32768;                  // 64*3*2048
constexpr int OUT_AVG  = OUT_ATTN + 393216;      // 425984
constexpr int OUT_TOPK = OUT_AVG + 131072;       // 557056
constexpr int OUT_ENT  = OUT_TOPK + 131072;      // 688128
constexpr int OUT_EFF  = OUT_ENT + 64;           // 688192
constexpr int OUT_T5   = OUT_EFF + 64;           // 688256

// ws layout (floats)
constexpr int WS_TK    = 0;                      // 131072
constexpr int WS_SC    = 131072;                 // [s*64+b][n] : 393216
constexpr int WS_STATS = WS_SC + 393216;         // 524288 : [b]=valid_sum, [64+b]=topk_sum
constexpr int WS_PART  = WS_STATS + 128;         // 524416 : [b*8+ch][5][256] = 655360
constexpr int WS_CAT   = WS_PART + 655360;       // 1179776 : [b][1280]
constexpr int WS_BFRAG = WS_CAT + 81920;         // 1261696 : 131072 bf16 = 65536 floats
// B-fragment layout: short index f = ((c*16 + ct)*64 + lane)*8 + j
//   k = c*32 + (lane>>4)*8 + j ; col = ct*16 + (lane&15)

typedef short  bf16x8 __attribute__((ext_vector_type(8)));
typedef float  f32x4  __attribute__((ext_vector_type(4)));

__device__ __forceinline__ short cvt_bf16(float f) {
    unsigned u = __float_as_uint(f);
    unsigned r = (u + 0x7FFFu + ((u >> 16) & 1u)) >> 16;
    return (short)r;
}
__device__ __forceinline__ float tanh_fast(float x) {
    float e = __expf(2.0f * x);      // v_exp based
    return 1.0f - 2.0f / (e + 1.0f); // saturates correctly at +/-1
}

__device__ __forceinline__ float block_sum256(float v, volatile float* red, int t) {
    #pragma unroll
    for (int off = 32; off; off >>= 1) v += __shfl_xor(v, off, 64);
    __syncthreads();
    if ((t & 63) == 0) red[t >> 6] = v;
    __syncthreads();
    return red[0] + red[1] + red[2] + red[3];
}
__device__ __forceinline__ float block_max256(float v, volatile float* red, int t) {
    #pragma unroll
    for (int off = 32; off; off >>= 1) v = fmaxf(v, __shfl_xor(v, off, 64));
    __syncthreads();
    if ((t & 63) == 0) red[t >> 6] = v;
    __syncthreads();
    return fmaxf(fmaxf(red[0], red[1]), fmaxf(red[2], red[3]));
}

// ---------------- K0: pack W = [Ws1 | Wa1_0 | Wa1_1 | Wa1_2] into bf16 B-fragments ----
__global__ __launch_bounds__(256)
void k_prep(const float* __restrict__ Ws1, const float* __restrict__ Wa1,
            short* __restrict__ wsB)
{
    const int id = blockIdx.x * 256 + threadIdx.x;   // 0..16383 : (c,ct,lane)
    if (id >= 16384) return;
    const int lane = id & 63, ct = (id >> 6) & 15, c = id >> 10;
    const int col = ct * 16 + (lane & 15);
    const int kb  = c * 32 + ((lane >> 4) << 3);
    bf16x8 v;
    #pragma unroll
    for (int j = 0; j < 8; ++j) {
        const int k = kb + j;
        float w = (col < 64) ? Ws1[(size_t)k * H_ + col]
                             : Wa1[(((size_t)(col >> 6) - 1) * D_ + k) * H_ + (col & 63)];
        v[j] = cvt_bf16(w);
    }
    *(bf16x8*)(wsB + (size_t)id * 8) = v;
}

// ---------------- K1: MFMA scorer + 3 attention-branch GEMM ----------------
// C[131072x256] = X @ [Ws1 | Wa1_0 | Wa1_1 | Wa1_2], epilogue relu/tanh + dot(W2).
__global__ __launch_bounds__(256, 4)
void k_scores(const float* __restrict__ inst, const float* __restrict__ mask,
              const short* __restrict__ wsB,
              const float* __restrict__ bs1, const float* __restrict__ Ws2,
              const float* __restrict__ bs2,
              const float* __restrict__ ba1, const float* __restrict__ Wa2,
              const float* __restrict__ ba2,
              float* __restrict__ ws)
{
    __shared__ short lbs[16 * 64 * 8];           // 16 KB: one K-chunk of B frags
    const int t = threadIdx.x;
    const int w = t >> 6, l = t & 63;
    const int rg = l >> 4, li = l & 15;
    const int row0 = blockIdx.x * 64;
    const int myrow = row0 + w * 16 + li;        // A-frag row for this lane

    f32x4 acc[16];
    #pragma unroll
    for (int ct = 0; ct < 16; ++ct) acc[ct] = (f32x4){0.f, 0.f, 0.f, 0.f};

    const float* xrow = inst + (size_t)myrow * D_;

    for (int c = 0; c < 8; ++c) {
        // stage 16 KB of B fragments (contiguous, coalesced)
        {
            float4* dst = (float4*)lbs;
            const float4* src = (const float4*)(wsB + (size_t)c * 8192);
            #pragma unroll
            for (int i = 0; i < 4; ++i) dst[t + 256 * i] = src[t + 256 * i];
        }
        __syncthreads();

        // A fragment: X[myrow][c*32 + rg*8 .. +7] -> bf16x8
        const int kb = c * 32 + rg * 8;
        float4 x0 = *(const float4*)(xrow + kb);
        float4 x1 = *(const float4*)(xrow + kb + 4);
        bf16x8 a;
        a[0] = cvt_bf16(x0.x); a[1] = cvt_bf16(x0.y);
        a[2] = cvt_bf16(x0.z); a[3] = cvt_bf16(x0.w);
        a[4] = cvt_bf16(x1.x); a[5] = cvt_bf16(x1.y);
        a[6] = cvt_bf16(x1.z); a[7] = cvt_bf16(x1.w);

        #pragma unroll
        for (int ct = 0; ct < 16; ++ct) {
            bf16x8 b = ((const bf16x8*)lbs)[ct * 64 + l];
            acc[ct] = __builtin_amdgcn_mfma_f32_16x16x32_bf16(a, b, acc[ct], 0, 0, 0);
        }
        __syncthreads();
    }

    // epilogue: per lane, acc[ct][i] = C[row0 + w*16 + rg*4 + i][ct*16 + li]
    float bias[16], w2v[16];
    #pragma unroll
    for (int ct = 0; ct < 16; ++ct) {
        const int col = ct * 16 + li;
        const int s = col >> 6, h = col & 63;
        if (s == 0) { bias[ct] = bs1[h];               w2v[ct] = Ws2[h]; }
        else        { bias[ct] = ba1[(s - 1) * H_ + h]; w2v[ct] = Wa2[(s - 1) * H_ + h]; }
    }
    const float bs2_v = bs2[0];
    float ba2_v[3] = {ba2[0], ba2[1], ba2[2]};

    #pragma unroll
    for (int s = 0; s < 4; ++s) {
        float res[4];
        #pragma unroll
        for (int i = 0; i < 4; ++i) {
            float p = 0.0f;
            #pragma unroll
            for (int q = 0; q < 4; ++q) {
                const int ct = s * 4 + q;
                float v = acc[ct][i] + bias[ct];
                p += (s == 0 ? fmaxf(v, 0.0f) : tanh_fast(v)) * w2v[ct];
            }
            #pragma unroll
            for (int off = 1; off < 16; off <<= 1) p += __shfl_xor(p, off, 64);
            res[i] = p;
        }
        if (li == 0) {
            #pragma unroll
            for (int i = 0; i < 4; ++i) {
                const int gr = row0 + w * 16 + rg * 4 + i;
                const bool inv = (mask[gr] == 0.0f);
                float val = res[i] + (s == 0 ? bs2_v : ba2_v[s - 1]);
                float* dst = (s == 0) ? (ws + WS_TK + gr)
                                      : (ws + WS_SC + (size_t)(s - 1) * M_ + gr);
                *dst = inv ? NEGINF_ : val;
            }
        }
    }
}

// ---------------- K2: per-batch top-204 via bitonic sort ----------------
__global__ __launch_bounds__(256)
void k_topk(const float* __restrict__ ws_tk, const float* __restrict__ mask,
            float* __restrict__ out_topk, float* __restrict__ ws_stats)
{
    __shared__ unsigned long long key[N_];      // 16 KB
    __shared__ float red[4];
    const int b = blockIdx.x, t = threadIdx.x;
    float vsum = 0.0f;
    for (int i = t; i < N_; i += 256) {
        float f = ws_tk[b * N_ + i];
        unsigned u = __float_as_uint(f);
        u = (u & 0x80000000u) ? ~u : (u | 0x80000000u);
        key[i] = ((unsigned long long)u << 32) | (unsigned)(N_ - 1 - i);
        vsum += mask[b * N_ + i];
        out_topk[b * N_ + i] = 0.0f;
    }
    float vs = block_sum256(vsum, red, t);
    if (t == 0) ws_stats[b] = vs;
    __syncthreads();
    for (int k = 2; k <= N_; k <<= 1) {
        for (int j = k >> 1; j > 0; j >>= 1) {
            for (int i = t; i < N_; i += 256) {
                int ij = i ^ j;
                if (ij > i) {
                    unsigned long long a = key[i], c = key[ij];
                    if ((a > c) == ((i & k) == 0)) { key[i] = c; key[ij] = a; }
                }
            }
            __syncthreads();
        }
    }
    float csum = 0.0f;
    for (int i = t; i < TOPK_; i += 256) {
        unsigned long long kk = key[N_ - 1 - i];
        int n = N_ - 1 - (int)(unsigned)(kk & 0xffffffffu);
        out_topk[b * N_ + n] = 1.0f;
        csum += mask[b * N_ + n];
    }
    float cs = block_sum256(csum, red, t);
    if (t == 0) ws_stats[64 + b] = cs;
}

// ---------------- K3: softmax per (branch, batch) ----------------
__global__ __launch_bounds__(256)
void k_softmax(const float* __restrict__ ws_sc, float* __restrict__ out_attn)
{
    __shared__ float red[4];
    const int sb = blockIdx.x;                  // s*64 + b
    const int s = sb >> 6, b = sb & 63;
    const int t = threadIdx.x;
    const float* src = ws_sc + (size_t)sb * N_;
    float fv[8];
    float mx = -3.4e38f;
    #pragma unroll
    for (int m = 0; m < 8; ++m) { fv[m] = src[t + 256 * m]; mx = fmaxf(mx, fv[m]); }
    float bm = block_max256(mx, red, t);
    float sm = 0.0f;
    #pragma unroll
    for (int m = 0; m < 8; ++m) { fv[m] = expf(fv[m] - bm); sm += fv[m]; }
    float tot = block_sum256(sm, red, t);
    float inv = 1.0f / tot;
    float* dst = out_attn + ((size_t)b * 3 + s) * N_;
    #pragma unroll
    for (int m = 0; m < 8; ++m) dst[t + 256 * m] = fv[m] * inv;
}

// ---------------- K4: pooling partials (mean, topk, 3 branches) ----------------
__global__ __launch_bounds__(256)
void k_pool(const float* __restrict__ inst, const float* __restrict__ mask,
            const float* __restrict__ out_topk, const float* __restrict__ out_attn,
            float* __restrict__ ws_part)
{
    __shared__ float wgt[5][256];
    const int blk = blockIdx.x;                 // b*8 + ch
    const int b = blk >> 3, ch = blk & 7;
    const int n0 = ch * 256;
    const int t = threadIdx.x;                  // = d
    {
        float mv = mask[b * N_ + n0 + t];
        wgt[0][t] = mv;
        wgt[1][t] = out_topk[b * N_ + n0 + t] * mv;
        const float* ab = out_attn + (size_t)b * 3 * N_ + n0 + t;
        wgt[2][t] = ab[0];
        wgt[3][t] = ab[N_];
        wgt[4][t] = ab[2 * N_];
    }
    __syncthreads();
    float a0 = 0, a1 = 0, a2 = 0, a3 = 0, a4 = 0;
    const float* xp = inst + ((size_t)b * N_ + n0) * D_ + t;
    #pragma unroll 4
    for (int nn = 0; nn < 256; ++nn) {
        float x = xp[(size_t)nn * D_];
        a0 = fmaf(x, wgt[0][nn], a0);
        a1 = fmaf(x, wgt[1][nn], a1);
        a2 = fmaf(x, wgt[2][nn], a2);
        a3 = fmaf(x, wgt[3][nn], a3);
        a4 = fmaf(x, wgt[4][nn], a4);
    }
    float* pp = ws_part + (size_t)blk * 1280 + t;
    pp[0] = a0; pp[256] = a1; pp[512] = a2; pp[768] = a3; pp[1024] = a4;
}

// ---------------- K5: reduce partials -> cat[b][1280] with scaling ----------------
__global__ __launch_bounds__(256)
void k_cat(const float* __restrict__ ws_part, const float* __restrict__ ws_stats,
           float* __restrict__ ws_cat)
{
    const int idx = blockIdx.x * 256 + threadIdx.x;
    if (idx >= B_ * 1280) return;
    const int b = idx / 1280, rem = idx % 1280;
    const int j = rem >> 8, d = rem & 255;
    float s = 0.0f;
    #pragma unroll
    for (int c = 0; c < 8; ++c)
        s += ws_part[((size_t)(b * 8 + c) * 5 + j) * 256 + d];
    if (j == 0)      s /= fmaxf(ws_stats[b], 1.0f);
    else if (j == 1) s /= fmaxf(ws_stats[64 + b], 1.0f);
    ws_cat[idx] = s;
}

// ---------------- K6: diagnostics (avg_attn, entropy, effective_n, top5) ----------------
__global__ __launch_bounds__(256)
void k_diag(const float* __restrict__ out_attn, float* __restrict__ out_avg,
            float* __restrict__ out_ent, float* __restrict__ out_eff,
            float* __restrict__ out_t5)
{
    __shared__ unsigned long long key[N_];
    __shared__ float red[4];
    const int b = blockIdx.x, t = threadIdx.x;
    const float* a0 = out_attn + (size_t)b * 3 * N_;
    float esum = 0.0f, qsum = 0.0f;
    for (int i = t; i < N_; i += 256) {
        float a = (a0[i] + a0[N_ + i] + a0[2 * N_ + i]) * (1.0f / 3.0f);
        out_avg[b * N_ + i] = a;
        esum -= a * logf(a + 1e-8f);
        qsum += a * a;
        unsigned u = __float_as_uint(a);
        u = (u & 0x80000000u) ? ~u : (u | 0x80000000u);
        key[i] = ((unsigned long long)u << 32) | (unsigned)i;
    }
    float es = block_sum256(esum, red, t);
    float qs = block_sum256(qsum, red, t);
    if (t == 0) { out_ent[b] = es; out_eff[b] = 1.0f / qs; }
    __syncthreads();
    for (int k = 2; k <= N_; k <<= 1) {
        for (int j = k >> 1; j > 0; j >>= 1) {
            for (int i = t; i < N_; i += 256) {
                int ij = i ^ j;
                if (ij > i) {
                    unsigned long long x = key[i], y = key[ij];
                    if ((x > y) == ((i & k) == 0)) { key[i] = y; key[ij] = x; }
                }
            }
            __syncthreads();
        }
    }
    if (t == 0) {
        float s5 = 0.0f;
        for (int i = 0; i < TOP5_; ++i) {
            unsigned ou = (unsigned)(key[N_ - 1 - i] >> 32);
            unsigned bits = (ou & 0x80000000u) ? (ou & 0x7fffffffu) : ~ou;
            s5 += __uint_as_float(bits);
        }
        out_t5[b] = s5;
    }
}

// ---------------- K7: fusion MLP (Linear -> LN -> GELU(erf) -> Linear) ----------------
__global__ __launch_bounds__(256)
void k_fusion(const float* __restrict__ ws_cat, const float* __restrict__ Wf1,
              const float* __restrict__ bf1, const float* __restrict__ ln_g,
              const float* __restrict__ ln_b, const float* __restrict__ Wf2,
              const float* __restrict__ bf2, float* __restrict__ out_bag)
{
    __shared__ float cl[1280];
    __shared__ float gl[512];
    __shared__ float red[4];
    const int b = blockIdx.x, t = threadIdx.x;
    for (int i = t; i < 1280; i += 256) cl[i] = ws_cat[b * 1280 + i];
    __syncthreads();
    float x0 = bf1[t], x1 = bf1[t + 256];
    #pragma unroll 4
    for (int k = 0; k < 1280; ++k) {
        float cv = cl[k];
        x0 = fmaf(cv, Wf1[(size_t)k * 512 + t], x0);
        x1 = fmaf(cv, Wf1[(size_t)k * 512 + t + 256], x1);
    }
    float mu = block_sum256(x0 + x1, red, t) * (1.0f / 512.0f);
    float v0 = x0 - mu, v1 = x1 - mu;
    float var = block_sum256(v0 * v0 + v1 * v1, red, t) * (1.0f / 512.0f);
    float is = 1.0f / sqrtf(var + 1e-5f);
    float y0 = v0 * is * ln_g[t] + ln_b[t];
    float y1 = v1 * is * ln_g[t + 256] + ln_b[t + 256];
    float g0 = 0.5f * y0 * (1.0f + erff(y0 * 0.70710678118654752440f));
    float g1 = 0.5f * y1 * (1.0f + erff(y1 * 0.70710678118654752440f));
    gl[t] = g0; gl[t + 256] = g1;
    __syncthreads();
    float o0 = bf2[t], o1 = bf2[t + 256];
    #pragma unroll 4
    for (int k = 0; k < 512; ++k) {
        float gv = gl[k];
        o0 = fmaf(gv, Wf2[(size_t)k * 512 + t], o0);
        o1 = fmaf(gv, Wf2[(size_t)k * 512 + t + 256], o1);
    }
    out_bag[b * 512 + t] = o0;
    out_bag[b * 512 + t + 256] = o1;
}

extern "C" void kernel_launch(void* const* d_in, const int* in_sizes, int n_in,
                              void* d_out, int out_size, void* d_ws, size_t ws_size,
                              hipStream_t stream)
{
    (void)in_sizes; (void)n_in; (void)out_size; (void)ws_size;
    const float* inst = (const float*)d_in[0];
    const float* mask = (const float*)d_in[1];
    const float* Ws1  = (const float*)d_in[2];
    const float* bs1  = (const float*)d_in[3];
    const float* Ws2  = (const float*)d_in[4];
    const float* bs2  = (const float*)d_in[5];
    const float* Wa1  = (const float*)d_in[6];
    const float* ba1  = (const float*)d_in[7];
    const float* Wa2  = (const float*)d_in[8];
    const float* ba2  = (const float*)d_in[9];
    const float* Wf1  = (const float*)d_in[10];
    const float* bf1  = (const float*)d_in[11];
    const float* lng  = (const float*)d_in[12];
    const float* lnb  = (const float*)d_in[13];
    const float* Wf2  = (const float*)d_in[14];
    const float* bf2  = (const float*)d_in[15];

    float* out = (float*)d_out;
    float* ws  = (float*)d_ws;
    short* wsB = (short*)(ws + WS_BFRAG);

    k_prep<<<64, 256, 0, stream>>>(Ws1, Wa1, wsB);
    k_scores<<<M_ / 64, 256, 0, stream>>>(inst, mask, wsB, bs1, Ws2, bs2,
                                          ba1, Wa2, ba2, ws);
    k_topk<<<B_, 256, 0, stream>>>(ws + WS_TK, mask, out + OUT_TOPK, ws + WS_STATS);
    k_softmax<<<3 * B_, 256, 0, stream>>>(ws + WS_SC, out + OUT_ATTN);
    k_pool<<<B_ * 8, 256, 0, stream>>>(inst, mask, out + OUT_TOPK, out + OUT_ATTN,
                                       ws + WS_PART);
    k_diag<<<B_, 256, 0, stream>>>(out + OUT_ATTN, out + OUT_AVG, out + OUT_ENT,
                                   out + OUT_EFF, out + OUT_T5);
    k_cat<<<(B_ * 1280 + 255) / 256, 256, 0, stream>>>(ws + WS_PART, ws + WS_STATS,
                                                       ws + WS_CAT);
    k_fusion<<<B_, 256, 0, stream>>>(ws + WS_CAT, Wf1, bf1, lng, lnb, Wf2, bf2,
                                     out + OUT_BAG);
}

// Round 4
// 435.803 us; speedup vs baseline: 3.0306x; 1.3736x over previous
//
#include <hip/hip_runtime.h>
#include <stdint.h>

constexpr int B_ = 64, N_ = 2048, D_ = 256, H_ = 64;
constexpr int M_ = B_ * N_;           // 131072 rows
constexpr int TOPK_ = 204, TOP5_ = 102;
constexpr float NEGINF_ = -1e30f;

// out layout (floats)
constexpr int OUT_BAG  = 0;                      // 64*512
constexpr int OUT_ATTN = 32768;                  // 64*3*2048
constexpr int OUT_AVG  = OUT_ATTN + 393216;      // 425984
constexpr int OUT_TOPK = OUT_AVG + 131072;       // 557056
constexpr int OUT_ENT  = OUT_TOPK + 131072;      // 688128
constexpr int OUT_EFF  = OUT_ENT + 64;           // 688192
constexpr int OUT_T5   = OUT_EFF + 64;           // 688256

// ws layout (floats)
constexpr int WS_TK    = 0;                      // 131072
constexpr int WS_SC    = 131072;                 // [s*64+b][n] : 393216
constexpr int WS_STATS = WS_SC + 393216;         // 524288 : [b]=valid_sum, [64+b]=topk_sum
constexpr int WS_PART  = WS_STATS + 128;         // 524416 : [b*8+ch][5][256] = 655360
constexpr int WS_CAT   = WS_PART + 655360;       // 1179776 : [b][1280]
constexpr int WS_BFRAG = WS_CAT + 81920;         // 1261696 : 131072 bf16 = 65536 floats
constexpr int WS_X1    = WS_BFRAG + 32768;       // 1294464 : [b][512]
constexpr int WS_G     = WS_X1 + 32768;          // 1327232 : [b][512]
// B-fragment layout: short index f = ((c*16 + ct)*64 + lane)*8 + j
//   k = c*32 + (lane>>4)*8 + j ; col = ct*16 + (lane&15)

typedef short  bf16x8 __attribute__((ext_vector_type(8)));
typedef float  f32x4  __attribute__((ext_vector_type(4)));

__device__ __forceinline__ short cvt_bf16(float f) {
    unsigned u = __float_as_uint(f);
    unsigned r = (u + 0x7FFFu + ((u >> 16) & 1u)) >> 16;
    return (short)r;
}
__device__ __forceinline__ float tanh_fast(float x) {
    float e = __expf(2.0f * x);      // v_exp based
    return 1.0f - 2.0f / (e + 1.0f); // saturates correctly at +/-1
}

__device__ __forceinline__ float block_sum256(float v, volatile float* red, int t) {
    #pragma unroll
    for (int off = 32; off; off >>= 1) v += __shfl_xor(v, off, 64);
    __syncthreads();
    if ((t & 63) == 0) red[t >> 6] = v;
    __syncthreads();
    return red[0] + red[1] + red[2] + red[3];
}
__device__ __forceinline__ float block_max256(float v, volatile float* red, int t) {
    #pragma unroll
    for (int off = 32; off; off >>= 1) v = fmaxf(v, __shfl_xor(v, off, 64));
    __syncthreads();
    if ((t & 63) == 0) red[t >> 6] = v;
    __syncthreads();
    return fmaxf(fmaxf(red[0], red[1]), fmaxf(red[2], red[3]));
}

// ---------------- K0: pack W = [Ws1 | Wa1_0 | Wa1_1 | Wa1_2] into bf16 B-fragments ----
__global__ __launch_bounds__(256)
void k_prep(const float* __restrict__ Ws1, const float* __restrict__ Wa1,
            short* __restrict__ wsB)
{
    const int id = blockIdx.x * 256 + threadIdx.x;   // 0..16383 : (c,ct,lane)
    if (id >= 16384) return;
    const int lane = id & 63, ct = (id >> 6) & 15, c = id >> 10;
    const int col = ct * 16 + (lane & 15);
    const int kb  = c * 32 + ((lane >> 4) << 3);
    bf16x8 v;
    #pragma unroll
    for (int j = 0; j < 8; ++j) {
        const int k = kb + j;
        float w = (col < 64) ? Ws1[(size_t)k * H_ + col]
                             : Wa1[(((size_t)(col >> 6) - 1) * D_ + k) * H_ + (col & 63)];
        v[j] = cvt_bf16(w);
    }
    *(bf16x8*)(wsB + (size_t)id * 8) = v;
}

// ---------------- K1: MFMA scorer + 3 attention-branch GEMM ----------------
__global__ __launch_bounds__(256, 4)
void k_scores(const float* __restrict__ inst, const float* __restrict__ mask,
              const short* __restrict__ wsB,
              const float* __restrict__ bs1, const float* __restrict__ Ws2,
              const float* __restrict__ bs2,
              const float* __restrict__ ba1, const float* __restrict__ Wa2,
              const float* __restrict__ ba2,
              float* __restrict__ ws)
{
    __shared__ short lbs[16 * 64 * 8];           // 16 KB: one K-chunk of B frags
    const int t = threadIdx.x;
    const int w = t >> 6, l = t & 63;
    const int rg = l >> 4, li = l & 15;
    const int row0 = blockIdx.x * 64;
    const int myrow = row0 + w * 16 + li;        // A-frag row for this lane

    f32x4 acc[16];
    #pragma unroll
    for (int ct = 0; ct < 16; ++ct) acc[ct] = (f32x4){0.f, 0.f, 0.f, 0.f};

    const float* xrow = inst + (size_t)myrow * D_;

    for (int c = 0; c < 8; ++c) {
        {
            float4* dst = (float4*)lbs;
            const float4* src = (const float4*)(wsB + (size_t)c * 8192);
            #pragma unroll
            for (int i = 0; i < 4; ++i) dst[t + 256 * i] = src[t + 256 * i];
        }
        __syncthreads();

        const int kb = c * 32 + rg * 8;
        float4 x0 = *(const float4*)(xrow + kb);
        float4 x1 = *(const float4*)(xrow + kb + 4);
        bf16x8 a;
        a[0] = cvt_bf16(x0.x); a[1] = cvt_bf16(x0.y);
        a[2] = cvt_bf16(x0.z); a[3] = cvt_bf16(x0.w);
        a[4] = cvt_bf16(x1.x); a[5] = cvt_bf16(x1.y);
        a[6] = cvt_bf16(x1.z); a[7] = cvt_bf16(x1.w);

        #pragma unroll
        for (int ct = 0; ct < 16; ++ct) {
            bf16x8 b = ((const bf16x8*)lbs)[ct * 64 + l];
            acc[ct] = __builtin_amdgcn_mfma_f32_16x16x32_bf16(a, b, acc[ct], 0, 0, 0);
        }
        __syncthreads();
    }

    float bias[16], w2v[16];
    #pragma unroll
    for (int ct = 0; ct < 16; ++ct) {
        const int col = ct * 16 + li;
        const int s = col >> 6, h = col & 63;
        if (s == 0) { bias[ct] = bs1[h];               w2v[ct] = Ws2[h]; }
        else        { bias[ct] = ba1[(s - 1) * H_ + h]; w2v[ct] = Wa2[(s - 1) * H_ + h]; }
    }
    const float bs2_v = bs2[0];
    float ba2_v[3] = {ba2[0], ba2[1], ba2[2]};

    #pragma unroll
    for (int s = 0; s < 4; ++s) {
        float res[4];
        #pragma unroll
        for (int i = 0; i < 4; ++i) {
            float p = 0.0f;
            #pragma unroll
            for (int q = 0; q < 4; ++q) {
                const int ct = s * 4 + q;
                float v = acc[ct][i] + bias[ct];
                p += (s == 0 ? fmaxf(v, 0.0f) : tanh_fast(v)) * w2v[ct];
            }
            #pragma unroll
            for (int off = 1; off < 16; off <<= 1) p += __shfl_xor(p, off, 64);
            res[i] = p;
        }
        if (li == 0) {
            #pragma unroll
            for (int i = 0; i < 4; ++i) {
                const int gr = row0 + w * 16 + rg * 4 + i;
                const bool inv = (mask[gr] == 0.0f);
                float val = res[i] + (s == 0 ? bs2_v : ba2_v[s - 1]);
                float* dst = (s == 0) ? (ws + WS_TK + gr)
                                      : (ws + WS_SC + (size_t)(s - 1) * M_ + gr);
                *dst = inv ? NEGINF_ : val;
            }
        }
    }
}

// ---------------- K2: per-batch top-204 via bitonic sort ----------------
__global__ __launch_bounds__(256)
void k_topk(const float* __restrict__ ws_tk, const float* __restrict__ mask,
            float* __restrict__ out_topk, float* __restrict__ ws_stats)
{
    __shared__ unsigned long long key[N_];      // 16 KB
    __shared__ float red[4];
    const int b = blockIdx.x, t = threadIdx.x;
    float vsum = 0.0f;
    for (int i = t; i < N_; i += 256) {
        float f = ws_tk[b * N_ + i];
        unsigned u = __float_as_uint(f);
        u = (u & 0x80000000u) ? ~u : (u | 0x80000000u);
        key[i] = ((unsigned long long)u << 32) | (unsigned)(N_ - 1 - i);
        vsum += mask[b * N_ + i];
        out_topk[b * N_ + i] = 0.0f;
    }
    float vs = block_sum256(vsum, red, t);
    if (t == 0) ws_stats[b] = vs;
    __syncthreads();
    for (int k = 2; k <= N_; k <<= 1) {
        for (int j = k >> 1; j > 0; j >>= 1) {
            for (int i = t; i < N_; i += 256) {
                int ij = i ^ j;
                if (ij > i) {
                    unsigned long long a = key[i], c = key[ij];
                    if ((a > c) == ((i & k) == 0)) { key[i] = c; key[ij] = a; }
                }
            }
            __syncthreads();
        }
    }
    float csum = 0.0f;
    for (int i = t; i < TOPK_; i += 256) {
        unsigned long long kk = key[N_ - 1 - i];
        int n = N_ - 1 - (int)(unsigned)(kk & 0xffffffffu);
        out_topk[b * N_ + n] = 1.0f;
        csum += mask[b * N_ + n];
    }
    float cs = block_sum256(csum, red, t);
    if (t == 0) ws_stats[64 + b] = cs;
}

// ---------------- K3: softmax per (branch, batch) ----------------
__global__ __launch_bounds__(256)
void k_softmax(const float* __restrict__ ws_sc, float* __restrict__ out_attn)
{
    __shared__ float red[4];
    const int sb = blockIdx.x;                  // s*64 + b
    const int s = sb >> 6, b = sb & 63;
    const int t = threadIdx.x;
    const float* src = ws_sc + (size_t)sb * N_;
    float fv[8];
    float mx = -3.4e38f;
    #pragma unroll
    for (int m = 0; m < 8; ++m) { fv[m] = src[t + 256 * m]; mx = fmaxf(mx, fv[m]); }
    float bm = block_max256(mx, red, t);
    float sm = 0.0f;
    #pragma unroll
    for (int m = 0; m < 8; ++m) { fv[m] = expf(fv[m] - bm); sm += fv[m]; }
    float tot = block_sum256(sm, red, t);
    float inv = 1.0f / tot;
    float* dst = out_attn + ((size_t)b * 3 + s) * N_;
    #pragma unroll
    for (int m = 0; m < 8; ++m) dst[t + 256 * m] = fv[m] * inv;
}

// ---------------- K4: pooling partials (mean, topk, 3 branches) ----------------
__global__ __launch_bounds__(256)
void k_pool(const float* __restrict__ inst, const float* __restrict__ mask,
            const float* __restrict__ out_topk, const float* __restrict__ out_attn,
            float* __restrict__ ws_part)
{
    __shared__ float wgt[5][256];
    const int blk = blockIdx.x;                 // b*8 + ch
    const int b = blk >> 3, ch = blk & 7;
    const int n0 = ch * 256;
    const int t = threadIdx.x;                  // = d
    {
        float mv = mask[b * N_ + n0 + t];
        wgt[0][t] = mv;
        wgt[1][t] = out_topk[b * N_ + n0 + t] * mv;
        const float* ab = out_attn + (size_t)b * 3 * N_ + n0 + t;
        wgt[2][t] = ab[0];
        wgt[3][t] = ab[N_];
        wgt[4][t] = ab[2 * N_];
    }
    __syncthreads();
    float a0 = 0, a1 = 0, a2 = 0, a3 = 0, a4 = 0;
    const float* xp = inst + ((size_t)b * N_ + n0) * D_ + t;
    #pragma unroll 4
    for (int nn = 0; nn < 256; ++nn) {
        float x = xp[(size_t)nn * D_];
        a0 = fmaf(x, wgt[0][nn], a0);
        a1 = fmaf(x, wgt[1][nn], a1);
        a2 = fmaf(x, wgt[2][nn], a2);
        a3 = fmaf(x, wgt[3][nn], a3);
        a4 = fmaf(x, wgt[4][nn], a4);
    }
    float* pp = ws_part + (size_t)blk * 1280 + t;
    pp[0] = a0; pp[256] = a1; pp[512] = a2; pp[768] = a3; pp[1024] = a4;
}

// ---------------- K5: reduce partials -> cat[b][1280] with scaling ----------------
__global__ __launch_bounds__(256)
void k_cat(const float* __restrict__ ws_part, const float* __restrict__ ws_stats,
           float* __restrict__ ws_cat)
{
    const int idx = blockIdx.x * 256 + threadIdx.x;
    if (idx >= B_ * 1280) return;
    const int b = idx / 1280, rem = idx % 1280;
    const int j = rem >> 8, d = rem & 255;
    float s = 0.0f;
    #pragma unroll
    for (int c = 0; c < 8; ++c)
        s += ws_part[((size_t)(b * 8 + c) * 5 + j) * 256 + d];
    if (j == 0)      s /= fmaxf(ws_stats[b], 1.0f);
    else if (j == 1) s /= fmaxf(ws_stats[64 + b], 1.0f);
    ws_cat[idx] = s;
}

// ---------------- K6: diagnostics (avg_attn, entropy, effective_n, top5) ----------------
__global__ __launch_bounds__(256)
void k_diag(const float* __restrict__ out_attn, float* __restrict__ out_avg,
            float* __restrict__ out_ent, float* __restrict__ out_eff,
            float* __restrict__ out_t5)
{
    __shared__ unsigned long long key[N_];
    __shared__ float red[4];
    const int b = blockIdx.x, t = threadIdx.x;
    const float* a0 = out_attn + (size_t)b * 3 * N_;
    float esum = 0.0f, qsum = 0.0f;
    for (int i = t; i < N_; i += 256) {
        float a = (a0[i] + a0[N_ + i] + a0[2 * N_ + i]) * (1.0f / 3.0f);
        out_avg[b * N_ + i] = a;
        esum -= a * logf(a + 1e-8f);
        qsum += a * a;
        unsigned u = __float_as_uint(a);
        u = (u & 0x80000000u) ? ~u : (u | 0x80000000u);
        key[i] = ((unsigned long long)u << 32) | (unsigned)i;
    }
    float es = block_sum256(esum, red, t);
    float qs = block_sum256(qsum, red, t);
    if (t == 0) { out_ent[b] = es; out_eff[b] = 1.0f / qs; }
    __syncthreads();
    for (int k = 2; k <= N_; k <<= 1) {
        for (int j = k >> 1; j > 0; j >>= 1) {
            for (int i = t; i < N_; i += 256) {
                int ij = i ^ j;
                if (ij > i) {
                    unsigned long long x = key[i], y = key[ij];
                    if ((x > y) == ((i & k) == 0)) { key[i] = y; key[ij] = x; }
                }
            }
            __syncthreads();
        }
    }
    if (t == 0) {
        float s5 = 0.0f;
        for (int i = 0; i < TOP5_; ++i) {
            unsigned ou = (unsigned)(key[N_ - 1 - i] >> 32);
            unsigned bits = (ou & 0x80000000u) ? (ou & 0x7fffffffu) : ~ou;
            s5 += __uint_as_float(bits);
        }
        out_t5[b] = s5;
    }
}

// ---------------- K7a: x1 = cat @ Wf1 + bf1  (split-K GEMV, 512 blocks) ----------------
__global__ __launch_bounds__(256)
void k_fuse1(const float* __restrict__ ws_cat, const float* __restrict__ Wf1,
             const float* __restrict__ bf1, float* __restrict__ x1)
{
    __shared__ float cl[1280];
    __shared__ float part[256];
    const int blk = blockIdx.x;                 // b*8 + c
    const int b = blk >> 3, c = blk & 7;
    const int t = threadIdx.x;
    const int j = c * 64 + (t & 63);            // output col
    const int s = t >> 6;                       // K-slice (4 x 320)
    for (int i = t; i < 1280; i += 256) cl[i] = ws_cat[b * 1280 + i];
    __syncthreads();
    float acc = 0.0f;
    const float* wp = Wf1 + (size_t)(s * 320) * 512 + j;
    #pragma unroll 8
    for (int i = 0; i < 320; ++i)
        acc = fmaf(cl[s * 320 + i], wp[(size_t)i * 512], acc);
    part[t] = acc;
    __syncthreads();
    if (t < 64)
        x1[b * 512 + c * 64 + t] =
            part[t] + part[64 + t] + part[128 + t] + part[192 + t] + bf1[c * 64 + t];
}

// ---------------- K7b: LayerNorm + GELU(erf) ----------------
__global__ __launch_bounds__(256)
void k_fuse2(const float* __restrict__ x1, const float* __restrict__ ln_g,
             const float* __restrict__ ln_b, float* __restrict__ g)
{
    __shared__ float red[4];
    const int b = blockIdx.x, t = threadIdx.x;
    float v0 = x1[b * 512 + t], v1 = x1[b * 512 + 256 + t];
    float mu = block_sum256(v0 + v1, red, t) * (1.0f / 512.0f);
    float d0 = v0 - mu, d1 = v1 - mu;
    float var = block_sum256(d0 * d0 + d1 * d1, red, t) * (1.0f / 512.0f);
    float is = 1.0f / sqrtf(var + 1e-5f);
    float y0 = d0 * is * ln_g[t] + ln_b[t];
    float y1 = d1 * is * ln_g[t + 256] + ln_b[t + 256];
    g[b * 512 + t]       = 0.5f * y0 * (1.0f + erff(y0 * 0.70710678118654752440f));
    g[b * 512 + 256 + t] = 0.5f * y1 * (1.0f + erff(y1 * 0.70710678118654752440f));
}

// ---------------- K7c: bag = g @ Wf2 + bf2 ----------------
__global__ __launch_bounds__(256)
void k_fuse3(const float* __restrict__ g, const float* __restrict__ Wf2,
             const float* __restrict__ bf2, float* __restrict__ out_bag)
{
    __shared__ float gl[512];
    __shared__ float part[256];
    const int blk = blockIdx.x;                 // b*8 + c
    const int b = blk >> 3, c = blk & 7;
    const int t = threadIdx.x;
    const int j = c * 64 + (t & 63);
    const int s = t >> 6;                       // K-slice (4 x 128)
    for (int i = t; i < 512; i += 256) gl[i] = g[b * 512 + i];
    __syncthreads();
    float acc = 0.0f;
    const float* wp = Wf2 + (size_t)(s * 128) * 512 + j;
    #pragma unroll 8
    for (int i = 0; i < 128; ++i)
        acc = fmaf(gl[s * 128 + i], wp[(size_t)i * 512], acc);
    part[t] = acc;
    __syncthreads();
    if (t < 64)
        out_bag[b * 512 + c * 64 + t] =
            part[t] + part[64 + t] + part[128 + t] + part[192 + t] + bf2[c * 64 + t];
}

extern "C" void kernel_launch(void* const* d_in, const int* in_sizes, int n_in,
                              void* d_out, int out_size, void* d_ws, size_t ws_size,
                              hipStream_t stream)
{
    (void)in_sizes; (void)n_in; (void)out_size; (void)ws_size;
    const float* inst = (const float*)d_in[0];
    const float* mask = (const float*)d_in[1];
    const float* Ws1  = (const float*)d_in[2];
    const float* bs1  = (const float*)d_in[3];
    const float* Ws2  = (const float*)d_in[4];
    const float* bs2  = (const float*)d_in[5];
    const float* Wa1  = (const float*)d_in[6];
    const float* ba1  = (const float*)d_in[7];
    const float* Wa2  = (const float*)d_in[8];
    const float* ba2  = (const float*)d_in[9];
    const float* Wf1  = (const float*)d_in[10];
    const float* bf1  = (const float*)d_in[11];
    const float* lng  = (const float*)d_in[12];
    const float* lnb  = (const float*)d_in[13];
    const float* Wf2  = (const float*)d_in[14];
    const float* bf2  = (const float*)d_in[15];

    float* out = (float*)d_out;
    float* ws  = (float*)d_ws;
    short* wsB = (short*)(ws + WS_BFRAG);

    k_prep<<<64, 256, 0, stream>>>(Ws1, Wa1, wsB);
    k_scores<<<M_ / 64, 256, 0, stream>>>(inst, mask, wsB, bs1, Ws2, bs2,
                                          ba1, Wa2, ba2, ws);
    k_topk<<<B_, 256, 0, stream>>>(ws + WS_TK, mask, out + OUT_TOPK, ws + WS_STATS);
    k_softmax<<<3 * B_, 256, 0, stream>>>(ws + WS_SC, out + OUT_ATTN);
    k_pool<<<B_ * 8, 256, 0, stream>>>(inst, mask, out + OUT_TOPK, out + OUT_ATTN,
                                       ws + WS_PART);
    k_diag<<<B_, 256, 0, stream>>>(out + OUT_ATTN, out + OUT_AVG, out + OUT_ENT,
                                   out + OUT_EFF, out + OUT_T5);
    k_cat<<<(B_ * 1280 + 255) / 256, 256, 0, stream>>>(ws + WS_PART, ws + WS_STATS,
                                                       ws + WS_CAT);
    k_fuse1<<<B_ * 8, 256, 0, stream>>>(ws + WS_CAT, Wf1, bf1, ws + WS_X1);
    k_fuse2<<<B_, 256, 0, stream>>>(ws + WS_X1, lng, lnb, ws + WS_G);
    k_fuse3<<<B_ * 8, 256, 0, stream>>>(ws + WS_G, Wf2, bf2, out + OUT_BAG);
}

// Round 5
// 343.149 us; speedup vs baseline: 3.8489x; 1.2700x over previous
//
#include <hip/hip_runtime.h>
#include <stdint.h>

constexpr int B_ = 64, N_ = 2048, D_ = 256, H_ = 64;
constexpr int M_ = B_ * N_;           // 131072 rows
constexpr int TOPK_ = 204, TOP5_ = 102;
constexpr float NEGINF_ = -1e30f;

// out layout (floats)
constexpr int OUT_BAG  = 0;                      // 64*512
constexpr int OUT_ATTN = 32768;                  // 64*3*2048
constexpr int OUT_AVG  = OUT_ATTN + 393216;      // 425984
constexpr int OUT_TOPK = OUT_AVG + 131072;       // 557056
constexpr int OUT_ENT  = OUT_TOPK + 131072;      // 688128
constexpr int OUT_EFF  = OUT_ENT + 64;           // 688192
constexpr int OUT_T5   = OUT_EFF + 64;           // 688256

// ws layout (floats)
constexpr int WS_TK    = 0;                      // 131072
constexpr int WS_SC    = 131072;                 // [s*64+b][n] : 393216
constexpr int WS_STATS = WS_SC + 393216;         // 524288 : [b]=valid_sum, [64+b]=topk_sum
constexpr int WS_PART  = WS_STATS + 128;         // 524416 : [b*8+ch][5][256] = 655360
constexpr int WS_BFRAG = WS_PART + 655360;       // 1179776 : 131072 bf16 = 65536 floats
constexpr int WS_X1    = WS_BFRAG + 32768;       // 1212544 : [b][512]
constexpr int WS_G     = WS_X1 + 32768;          // 1245312 : [b][512]

typedef short  bf16x8 __attribute__((ext_vector_type(8)));
typedef float  f32x4  __attribute__((ext_vector_type(4)));

__device__ __forceinline__ short cvt_bf16(float f) {
    unsigned u = __float_as_uint(f);
    unsigned r = (u + 0x7FFFu + ((u >> 16) & 1u)) >> 16;
    return (short)r;
}
__device__ __forceinline__ float tanh_fast(float x) {
    float e = __expf(2.0f * x);
    return 1.0f - 2.0f / (e + 1.0f);
}
__device__ __forceinline__ unsigned flip_f32(float f) {
    unsigned u = __float_as_uint(f);
    return (u & 0x80000000u) ? ~u : (u | 0x80000000u);
}
__device__ __forceinline__ float unflip_f32(unsigned u) {
    unsigned b = (u & 0x80000000u) ? (u & 0x7FFFFFFFu) : ~u;
    return __uint_as_float(b);
}

__device__ __forceinline__ float block_sum256(float v, volatile float* red, int t) {
    #pragma unroll
    for (int off = 32; off; off >>= 1) v += __shfl_xor(v, off, 64);
    __syncthreads();
    if ((t & 63) == 0) red[t >> 6] = v;
    __syncthreads();
    return red[0] + red[1] + red[2] + red[3];
}
__device__ __forceinline__ float block_max256(float v, volatile float* red, int t) {
    #pragma unroll
    for (int off = 32; off; off >>= 1) v = fmaxf(v, __shfl_xor(v, off, 64));
    __syncthreads();
    if ((t & 63) == 0) red[t >> 6] = v;
    __syncthreads();
    return fmaxf(fmaxf(red[0], red[1]), fmaxf(red[2], red[3]));
}

// radix-select: exact key of the k-th largest among key[0..n) (flipped-float order).
// rem_out = how many ties (== returned key) belong in the top-k.
// hist: shared unsigned[256]; sdig: shared int; 256-thread block.
__device__ unsigned radix_kth(const unsigned* key, int n, int k,
                              unsigned* hist, int* sdig, int t, int* rem_out)
{
    unsigned prefix = 0;
    int kk = k;
    #pragma unroll
    for (int pass = 0; pass < 4; ++pass) {
        const int shift = 24 - 8 * pass;
        const unsigned hi_mask = (pass == 0) ? 0u : (0xFFFFFFFFu << (shift + 8));
        hist[t] = 0;
        __syncthreads();
        for (int i = t; i < n; i += 256) {
            unsigned u = key[i];
            if ((u & hi_mask) == (prefix & hi_mask))
                atomicAdd(&hist[(u >> shift) & 0xFFu], 1u);
        }
        __syncthreads();
        // suffix inclusive scan: hist[t] <- sum_{d>=t} hist[d]
        for (int s = 1; s < 256; s <<= 1) {
            unsigned v = (t + s < 256) ? hist[t + s] : 0u;
            __syncthreads();
            hist[t] += v;
            __syncthreads();
        }
        if (t == 0) *sdig = 0;
        __syncthreads();
        if ((int)hist[t] >= kk) atomicMax(sdig, t);
        __syncthreads();
        const int dig = *sdig;
        if (dig < 255) kk -= (int)hist[dig + 1];
        prefix |= (unsigned)dig << shift;
        __syncthreads();
    }
    *rem_out = kk;
    return prefix;
}

// ---------------- K0: pack W = [Ws1 | Wa1_0 | Wa1_1 | Wa1_2] into bf16 B-fragments ----
__global__ __launch_bounds__(256)
void k_prep(const float* __restrict__ Ws1, const float* __restrict__ Wa1,
            short* __restrict__ wsB)
{
    const int id = blockIdx.x * 256 + threadIdx.x;   // 0..16383 : (c,ct,lane)
    if (id >= 16384) return;
    const int lane = id & 63, ct = (id >> 6) & 15, c = id >> 10;
    const int col = ct * 16 + (lane & 15);
    const int kb  = c * 32 + ((lane >> 4) << 3);
    bf16x8 v;
    #pragma unroll
    for (int j = 0; j < 8; ++j) {
        const int k = kb + j;
        float w = (col < 64) ? Ws1[(size_t)k * H_ + col]
                             : Wa1[(((size_t)(col >> 6) - 1) * D_ + k) * H_ + (col & 63)];
        v[j] = cvt_bf16(w);
    }
    *(bf16x8*)(wsB + (size_t)id * 8) = v;
}

// ---------------- K1: MFMA scorer + 3 attention-branch GEMM ----------------
__global__ __launch_bounds__(256, 4)
void k_scores(const float* __restrict__ inst, const float* __restrict__ mask,
              const short* __restrict__ wsB,
              const float* __restrict__ bs1, const float* __restrict__ Ws2,
              const float* __restrict__ bs2,
              const float* __restrict__ ba1, const float* __restrict__ Wa2,
              const float* __restrict__ ba2,
              float* __restrict__ ws)
{
    __shared__ short lbs[16 * 64 * 8];           // 16 KB: one K-chunk of B frags
    const int t = threadIdx.x;
    const int w = t >> 6, l = t & 63;
    const int rg = l >> 4, li = l & 15;
    const int row0 = blockIdx.x * 64;
    const int myrow = row0 + w * 16 + li;

    f32x4 acc[16];
    #pragma unroll
    for (int ct = 0; ct < 16; ++ct) acc[ct] = (f32x4){0.f, 0.f, 0.f, 0.f};

    const float* xrow = inst + (size_t)myrow * D_;

    for (int c = 0; c < 8; ++c) {
        {
            float4* dst = (float4*)lbs;
            const float4* src = (const float4*)(wsB + (size_t)c * 8192);
            #pragma unroll
            for (int i = 0; i < 4; ++i) dst[t + 256 * i] = src[t + 256 * i];
        }
        __syncthreads();

        const int kb = c * 32 + rg * 8;
        float4 x0 = *(const float4*)(xrow + kb);
        float4 x1 = *(const float4*)(xrow + kb + 4);
        bf16x8 a;
        a[0] = cvt_bf16(x0.x); a[1] = cvt_bf16(x0.y);
        a[2] = cvt_bf16(x0.z); a[3] = cvt_bf16(x0.w);
        a[4] = cvt_bf16(x1.x); a[5] = cvt_bf16(x1.y);
        a[6] = cvt_bf16(x1.z); a[7] = cvt_bf16(x1.w);

        #pragma unroll
        for (int ct = 0; ct < 16; ++ct) {
            bf16x8 b = ((const bf16x8*)lbs)[ct * 64 + l];
            acc[ct] = __builtin_amdgcn_mfma_f32_16x16x32_bf16(a, b, acc[ct], 0, 0, 0);
        }
        __syncthreads();
    }

    float bias[16], w2v[16];
    #pragma unroll
    for (int ct = 0; ct < 16; ++ct) {
        const int col = ct * 16 + li;
        const int s = col >> 6, h = col & 63;
        if (s == 0) { bias[ct] = bs1[h];               w2v[ct] = Ws2[h]; }
        else        { bias[ct] = ba1[(s - 1) * H_ + h]; w2v[ct] = Wa2[(s - 1) * H_ + h]; }
    }
    const float bs2_v = bs2[0];
    float ba2_v[3] = {ba2[0], ba2[1], ba2[2]};

    #pragma unroll
    for (int s = 0; s < 4; ++s) {
        float res[4];
        #pragma unroll
        for (int i = 0; i < 4; ++i) {
            float p = 0.0f;
            #pragma unroll
            for (int q = 0; q < 4; ++q) {
                const int ct = s * 4 + q;
                float v = acc[ct][i] + bias[ct];
                p += (s == 0 ? fmaxf(v, 0.0f) : tanh_fast(v)) * w2v[ct];
            }
            #pragma unroll
            for (int off = 1; off < 16; off <<= 1) p += __shfl_xor(p, off, 64);
            res[i] = p;
        }
        if (li == 0) {
            #pragma unroll
            for (int i = 0; i < 4; ++i) {
                const int gr = row0 + w * 16 + rg * 4 + i;
                const bool inv = (mask[gr] == 0.0f);
                float val = res[i] + (s == 0 ? bs2_v : ba2_v[s - 1]);
                float* dst = (s == 0) ? (ws + WS_TK + gr)
                                      : (ws + WS_SC + (size_t)(s - 1) * M_ + gr);
                *dst = inv ? NEGINF_ : val;
            }
        }
    }
}

// ---------------- K2: per-batch top-204 via radix select ----------------
__global__ __launch_bounds__(256)
void k_topk(const float* __restrict__ ws_tk, const float* __restrict__ mask,
            float* __restrict__ out_topk, float* __restrict__ ws_stats)
{
    __shared__ unsigned ukey[N_];               // 8 KB
    __shared__ unsigned hist[256];
    __shared__ int sdig;
    __shared__ int tie_cnt;
    __shared__ float red[4];
    const int b = blockIdx.x, t = threadIdx.x;
    float vsum = 0.0f;
    for (int i = t; i < N_; i += 256) {
        ukey[i] = flip_f32(ws_tk[b * N_ + i]);
        vsum += mask[b * N_ + i];
        out_topk[b * N_ + i] = 0.0f;
    }
    float vs = block_sum256(vsum, red, t);
    if (t == 0) { ws_stats[b] = vs; tie_cnt = 0; }
    __syncthreads();
    int rem;
    const unsigned T = radix_kth(ukey, N_, TOPK_, hist, &sdig, t, &rem);
    float csum = 0.0f;
    for (int i = t; i < N_; i += 256) {
        const unsigned u = ukey[i];
        bool take = (u > T);
        if (!take && u == T) take = (atomicAdd(&tie_cnt, 1) < rem);
        if (take) {
            out_topk[b * N_ + i] = 1.0f;
            csum += mask[b * N_ + i];
        }
    }
    float cs = block_sum256(csum, red, t);
    if (t == 0) ws_stats[64 + b] = cs;
}

// ---------------- K3: softmax per (branch, batch) ----------------
__global__ __launch_bounds__(256)
void k_softmax(const float* __restrict__ ws_sc, float* __restrict__ out_attn)
{
    __shared__ float red[4];
    const int sb = blockIdx.x;                  // s*64 + b
    const int s = sb >> 6, b = sb & 63;
    const int t = threadIdx.x;
    const float* src = ws_sc + (size_t)sb * N_;
    float fv[8];
    float mx = -3.4e38f;
    #pragma unroll
    for (int m = 0; m < 8; ++m) { fv[m] = src[t + 256 * m]; mx = fmaxf(mx, fv[m]); }
    float bm = block_max256(mx, red, t);
    float sm = 0.0f;
    #pragma unroll
    for (int m = 0; m < 8; ++m) { fv[m] = expf(fv[m] - bm); sm += fv[m]; }
    float tot = block_sum256(sm, red, t);
    float inv = 1.0f / tot;
    float* dst = out_attn + ((size_t)b * 3 + s) * N_;
    #pragma unroll
    for (int m = 0; m < 8; ++m) dst[t + 256 * m] = fv[m] * inv;
}

// ---------------- K4: pooling partials, float4 loads ----------------
__global__ __launch_bounds__(256)
void k_pool(const float* __restrict__ inst, const float* __restrict__ mask,
            const float* __restrict__ out_topk, const float* __restrict__ out_attn,
            float* __restrict__ ws_part)
{
    __shared__ float wgt[5][256];
    __shared__ float4 partial[4][5][64];        // 20 KB
    const int blk = blockIdx.x;                 // b*8 + ch
    const int b = blk >> 3, ch = blk & 7;
    const int n0 = ch * 256;
    const int t = threadIdx.x;
    const int w = t >> 6, l = t & 63;
    {
        float mv = mask[b * N_ + n0 + t];
        wgt[0][t] = mv;
        wgt[1][t] = out_topk[b * N_ + n0 + t] * mv;
        const float* ab = out_attn + (size_t)b * 3 * N_ + n0 + t;
        wgt[2][t] = ab[0];
        wgt[3][t] = ab[N_];
        wgt[4][t] = ab[2 * N_];
    }
    __syncthreads();
    float4 a0 = {0,0,0,0}, a1 = {0,0,0,0}, a2 = {0,0,0,0}, a3 = {0,0,0,0}, a4 = {0,0,0,0};
    const float4* xp = (const float4*)(inst + ((size_t)b * N_ + n0 + w * 64) * D_) + l;
    #pragma unroll 4
    for (int nn = 0; nn < 64; ++nn) {
        float4 x = xp[(size_t)nn * 64];
        float w0 = wgt[0][w * 64 + nn], w1 = wgt[1][w * 64 + nn];
        float w2 = wgt[2][w * 64 + nn], w3 = wgt[3][w * 64 + nn];
        float w4 = wgt[4][w * 64 + nn];
        a0.x = fmaf(x.x, w0, a0.x); a0.y = fmaf(x.y, w0, a0.y);
        a0.z = fmaf(x.z, w0, a0.z); a0.w = fmaf(x.w, w0, a0.w);
        a1.x = fmaf(x.x, w1, a1.x); a1.y = fmaf(x.y, w1, a1.y);
        a1.z = fmaf(x.z, w1, a1.z); a1.w = fmaf(x.w, w1, a1.w);
        a2.x = fmaf(x.x, w2, a2.x); a2.y = fmaf(x.y, w2, a2.y);
        a2.z = fmaf(x.z, w2, a2.z); a2.w = fmaf(x.w, w2, a2.w);
        a3.x = fmaf(x.x, w3, a3.x); a3.y = fmaf(x.y, w3, a3.y);
        a3.z = fmaf(x.z, w3, a3.z); a3.w = fmaf(x.w, w3, a3.w);
        a4.x = fmaf(x.x, w4, a4.x); a4.y = fmaf(x.y, w4, a4.y);
        a4.z = fmaf(x.z, w4, a4.z); a4.w = fmaf(x.w, w4, a4.w);
    }
    partial[w][0][l] = a0; partial[w][1][l] = a1; partial[w][2][l] = a2;
    partial[w][3][l] = a3; partial[w][4][l] = a4;
    __syncthreads();
    for (int idx = t; idx < 320; idx += 256) {
        const int j = idx >> 6, l2 = idx & 63;
        float4 s0 = partial[0][j][l2], s1 = partial[1][j][l2];
        float4 s2 = partial[2][j][l2], s3 = partial[3][j][l2];
        float4 sm;
        sm.x = s0.x + s1.x + s2.x + s3.x;
        sm.y = s0.y + s1.y + s2.y + s3.y;
        sm.z = s0.z + s1.z + s2.z + s3.z;
        sm.w = s0.w + s1.w + s2.w + s3.w;
        *(float4*)(ws_part + (size_t)blk * 1280 + j * 256 + l2 * 4) = sm;
    }
}

// ---------------- K6: diagnostics with radix-select top-102 sum ----------------
__global__ __launch_bounds__(256)
void k_diag(const float* __restrict__ out_attn, float* __restrict__ out_avg,
            float* __restrict__ out_ent, float* __restrict__ out_eff,
            float* __restrict__ out_t5)
{
    __shared__ unsigned ukey[N_];               // 8 KB
    __shared__ unsigned hist[256];
    __shared__ int sdig;
    __shared__ float red[4];
    const int b = blockIdx.x, t = threadIdx.x;
    const float* a0 = out_attn + (size_t)b * 3 * N_;
    float esum = 0.0f, qsum = 0.0f;
    for (int i = t; i < N_; i += 256) {
        float a = (a0[i] + a0[N_ + i] + a0[2 * N_ + i]) * (1.0f / 3.0f);
        out_avg[b * N_ + i] = a;
        esum -= a * logf(a + 1e-8f);
        qsum += a * a;
        ukey[i] = flip_f32(a);
    }
    float es = block_sum256(esum, red, t);
    float qs = block_sum256(qsum, red, t);
    if (t == 0) { out_ent[b] = es; out_eff[b] = 1.0f / qs; }
    __syncthreads();
    int rem;
    const unsigned T = radix_kth(ukey, N_, TOP5_, hist, &sdig, t, &rem);
    float tsum = 0.0f;
    for (int i = t; i < N_; i += 256) {
        const unsigned u = ukey[i];
        if (u > T) tsum += unflip_f32(u);
    }
    float ts = block_sum256(tsum, red, t);
    if (t == 0) out_t5[b] = ts + (float)rem * unflip_f32(T);
}

// ---------------- K7a: x1 = cat @ Wf1 + bf1 (cat folded in; split-K GEMV) ----------
__global__ __launch_bounds__(256)
void k_fuse1(const float* __restrict__ ws_part, const float* __restrict__ ws_stats,
             const float* __restrict__ Wf1, const float* __restrict__ bf1,
             float* __restrict__ x1)
{
    __shared__ float cl[1280];
    __shared__ float part[256];
    const int blk = blockIdx.x;                 // b*8 + c
    const int b = blk >> 3, c = blk & 7;
    const int t = threadIdx.x;
    const float inv0 = 1.0f / fmaxf(ws_stats[b], 1.0f);
    const float inv1 = 1.0f / fmaxf(ws_stats[64 + b], 1.0f);
    for (int i = t; i < 1280; i += 256) {
        const int j = i >> 8, d = i & 255;
        float s = 0.0f;
        #pragma unroll
        for (int cc = 0; cc < 8; ++cc)
            s += ws_part[((size_t)(b * 8 + cc) * 5 + j) * 256 + d];
        if (j == 0)      s *= inv0;
        else if (j == 1) s *= inv1;
        cl[i] = s;
    }
    __syncthreads();
    const int j = c * 64 + (t & 63);
    const int s = t >> 6;
    float acc = 0.0f;
    const float* wp = Wf1 + (size_t)(s * 320) * 512 + j;
    #pragma unroll 8
    for (int i = 0; i < 320; ++i)
        acc = fmaf(cl[s * 320 + i], wp[(size_t)i * 512], acc);
    part[t] = acc;
    __syncthreads();
    if (t < 64)
        x1[b * 512 + c * 64 + t] =
            part[t] + part[64 + t] + part[128 + t] + part[192 + t] + bf1[c * 64 + t];
}

// ---------------- K7b: LayerNorm + GELU(erf) ----------------
__global__ __launch_bounds__(256)
void k_fuse2(const float* __restrict__ x1, const float* __restrict__ ln_g,
             const float* __restrict__ ln_b, float* __restrict__ g)
{
    __shared__ float red[4];
    const int b = blockIdx.x, t = threadIdx.x;
    float v0 = x1[b * 512 + t], v1 = x1[b * 512 + 256 + t];
    float mu = block_sum256(v0 + v1, red, t) * (1.0f / 512.0f);
    float d0 = v0 - mu, d1 = v1 - mu;
    float var = block_sum256(d0 * d0 + d1 * d1, red, t) * (1.0f / 512.0f);
    float is = 1.0f / sqrtf(var + 1e-5f);
    float y0 = d0 * is * ln_g[t] + ln_b[t];
    float y1 = d1 * is * ln_g[t + 256] + ln_b[t + 256];
    g[b * 512 + t]       = 0.5f * y0 * (1.0f + erff(y0 * 0.70710678118654752440f));
    g[b * 512 + 256 + t] = 0.5f * y1 * (1.0f + erff(y1 * 0.70710678118654752440f));
}

// ---------------- K7c: bag = g @ Wf2 + bf2 ----------------
__global__ __launch_bounds__(256)
void k_fuse3(const float* __restrict__ g, const float* __restrict__ Wf2,
             const float* __restrict__ bf2, float* __restrict__ out_bag)
{
    __shared__ float gl[512];
    __shared__ float part[256];
    const int blk = blockIdx.x;                 // b*8 + c
    const int b = blk >> 3, c = blk & 7;
    const int t = threadIdx.x;
    const int j = c * 64 + (t & 63);
    const int s = t >> 6;
    for (int i = t; i < 512; i += 256) gl[i] = g[b * 512 + i];
    __syncthreads();
    float acc = 0.0f;
    const float* wp = Wf2 + (size_t)(s * 128) * 512 + j;
    #pragma unroll 8
    for (int i = 0; i < 128; ++i)
        acc = fmaf(gl[s * 128 + i], wp[(size_t)i * 512], acc);
    part[t] = acc;
    __syncthreads();
    if (t < 64)
        out_bag[b * 512 + c * 64 + t] =
            part[t] + part[64 + t] + part[128 + t] + part[192 + t] + bf2[c * 64 + t];
}

extern "C" void kernel_launch(void* const* d_in, const int* in_sizes, int n_in,
                              void* d_out, int out_size, void* d_ws, size_t ws_size,
                              hipStream_t stream)
{
    (void)in_sizes; (void)n_in; (void)out_size; (void)ws_size;
    const float* inst = (const float*)d_in[0];
    const float* mask = (const float*)d_in[1];
    const float* Ws1  = (const float*)d_in[2];
    const float* bs1  = (const float*)d_in[3];
    const float* Ws2  = (const float*)d_in[4];
    const float* bs2  = (const float*)d_in[5];
    const float* Wa1  = (const float*)d_in[6];
    const float* ba1  = (const float*)d_in[7];
    const float* Wa2  = (const float*)d_in[8];
    const float* ba2  = (const float*)d_in[9];
    const float* Wf1  = (const float*)d_in[10];
    const float* bf1  = (const float*)d_in[11];
    const float* lng  = (const float*)d_in[12];
    const float* lnb  = (const float*)d_in[13];
    const float* Wf2  = (const float*)d_in[14];
    const float* bf2  = (const float*)d_in[15];

    float* out = (float*)d_out;
    float* ws  = (float*)d_ws;
    short* wsB = (short*)(ws + WS_BFRAG);

    k_prep<<<64, 256, 0, stream>>>(Ws1, Wa1, wsB);
    k_scores<<<M_ / 64, 256, 0, stream>>>(inst, mask, wsB, bs1, Ws2, bs2,
                                          ba1, Wa2, ba2, ws);
    k_topk<<<B_, 256, 0, stream>>>(ws + WS_TK, mask, out + OUT_TOPK, ws + WS_STATS);
    k_softmax<<<3 * B_, 256, 0, stream>>>(ws + WS_SC, out + OUT_ATTN);
    k_pool<<<B_ * 8, 256, 0, stream>>>(inst, mask, out + OUT_TOPK, out + OUT_ATTN,
                                       ws + WS_PART);
    k_diag<<<B_, 256, 0, stream>>>(out + OUT_ATTN, out + OUT_AVG, out + OUT_ENT,
                                   out + OUT_EFF, out + OUT_T5);
    k_fuse1<<<B_ * 8, 256, 0, stream>>>(ws + WS_PART, ws + WS_STATS, Wf1, bf1,
                                        ws + WS_X1);
    k_fuse2<<<B_, 256, 0, stream>>>(ws + WS_X1, lng, lnb, ws + WS_G);
    k_fuse3<<<B_ * 8, 256, 0, stream>>>(ws + WS_G, Wf2, bf2, out + OUT_BAG);
}